// Round 4
// baseline (1909.714 us; speedup 1.0000x reference)
//
#include <hip/hip_runtime.h>

// ---------------------------------------------------------------------------
// InteractionBlock: W = ssp(attr@w1+b1)@w2+b2; W *= cutoff(len);
// h = x@lin1_w; agg[dst] += h[src]*W; out = ssp(agg@lin2_w+b)@lin_w+b
// N=50000, E=1.6M, HID=NF=128, NG=64
// R6: pull with structural VMEM diet. R5 still spilled ~1GB (WRITE 986MB vs
//     26MB program writes) because the scheduler pipelines ~39 VMEM/batch.
//     Changes: (1) egather pass -> sorted bf16 eattr (2 streaming dwordx4 in
//     pull, no perm/no cvt); (2) TRANSPOSED layer-2 MFMA (operand swap) so
//     each lane owns one edge x 4-consecutive cols -> h-gather is 8 dwordx4
//     instead of 32 dwords, meta is one int2; (3) m-axis butterfly reduce.
//     VMEM/batch 39 -> 11.
// ---------------------------------------------------------------------------

typedef __attribute__((ext_vector_type(8))) short bf16x8;
typedef __attribute__((ext_vector_type(4))) float f32x4;

static __device__ __forceinline__ float sspf(float v) {
    return fmaxf(v, 0.0f) + __logf(1.0f + __expf(-fabsf(v))) - 0.69314718f;
}

// fp32 -> bf16 round-to-nearest-even
static __device__ __forceinline__ short bf16s(float x) {
    unsigned u = __builtin_bit_cast(unsigned, x);
    return (short)((u + 0x7fffu + ((u >> 16) & 1u)) >> 16);
}

// ---------------------------------------------------------------------------
// Kernel 1: h = x @ lin1_w   [N,128] = [N,128]@[128,128]  (fp32 vector)
// ---------------------------------------------------------------------------
__global__ __launch_bounds__(256) void node_proj_kernel(
    const float* __restrict__ x, const float* __restrict__ w,
    float* __restrict__ h, int n)
{
    __shared__ float xsT[128 * 20];   // [k][row], pitch 20 floats
    int row0 = blockIdx.x * 16;
    for (int i = threadIdx.x; i < 2048; i += 256) {
        int r = i >> 7, c = i & 127;
        int rr = row0 + r;
        xsT[c * 20 + r] = (rr < n) ? x[(size_t)rr * 128 + c] : 0.0f;
    }
    __syncthreads();
    int j = threadIdx.x & 127;
    int rb = (threadIdx.x >> 7) * 8;
    float acc[8] = {0, 0, 0, 0, 0, 0, 0, 0};
    for (int k = 0; k < 128; ++k) {
        float wk = w[k * 128 + j];
        const float4* xp = (const float4*)&xsT[k * 20 + rb];
        float4 u0 = xp[0], u1 = xp[1];
        acc[0] = fmaf(u0.x, wk, acc[0]);
        acc[1] = fmaf(u0.y, wk, acc[1]);
        acc[2] = fmaf(u0.z, wk, acc[2]);
        acc[3] = fmaf(u0.w, wk, acc[3]);
        acc[4] = fmaf(u1.x, wk, acc[4]);
        acc[5] = fmaf(u1.y, wk, acc[5]);
        acc[6] = fmaf(u1.z, wk, acc[6]);
        acc[7] = fmaf(u1.w, wk, acc[7]);
    }
#pragma unroll
    for (int r = 0; r < 8; ++r) {
        int rr = row0 + rb + r;
        if (rr < n) h[(size_t)rr * 128 + j] = acc[r];
    }
}

// ---------------------------------------------------------------------------
// Sort machinery: counting sort of edges by dst.
// ---------------------------------------------------------------------------
__global__ __launch_bounds__(256) void hist_kernel(
    const int* __restrict__ eidx, int* __restrict__ counts, int E)
{
    int i = blockIdx.x * 256 + threadIdx.x;
    int stride = gridDim.x * 256;
    for (; i < E; i += stride) atomicAdd(&counts[eidx[E + i]], 1);
}

// exclusive scan of counts[0..n-1] -> off[0..n] and cursor copy; 1 block.
// 4 elements per thread per round (13 rounds at n=50000).
__global__ __launch_bounds__(1024) void scan_kernel(
    const int* __restrict__ counts, int* __restrict__ off,
    int* __restrict__ cursor, int n)
{
    __shared__ int wsum[16];
    __shared__ int carry_s;
    int t = threadIdx.x;
    int lane = t & 63, w = t >> 6;
    if (t == 0) carry_s = 0;
    __syncthreads();
    for (int base = 0; base < n; base += 4096) {
        int i0 = base + t * 4;
        int v0 = (i0 < n) ? counts[i0] : 0;
        int v1 = (i0 + 1 < n) ? counts[i0 + 1] : 0;
        int v2 = (i0 + 2 < n) ? counts[i0 + 2] : 0;
        int v3 = (i0 + 3 < n) ? counts[i0 + 3] : 0;
        int lsum = v0 + v1 + v2 + v3;
        int s = lsum;
#pragma unroll
        for (int d = 1; d < 64; d <<= 1) {
            int u = __shfl_up(s, d, 64);
            if (lane >= d) s += u;
        }
        if (lane == 63) wsum[w] = s;
        __syncthreads();
        if (w == 0) {
            int ws = (lane < 16) ? wsum[lane] : 0;
#pragma unroll
            for (int d = 1; d < 16; d <<= 1) {
                int u = __shfl_up(ws, d, 64);
                if (lane >= d) ws += u;
            }
            if (lane < 16) wsum[lane] = ws;   // inclusive wave totals
        }
        __syncthreads();
        int waveoff = (w > 0) ? wsum[w - 1] : 0;
        int total = wsum[15];
        int e = carry_s + waveoff + s - lsum;
        if (i0 < n)     { off[i0] = e;               cursor[i0] = e; }
        if (i0 + 1 < n) { off[i0 + 1] = e + v0;      cursor[i0 + 1] = e + v0; }
        if (i0 + 2 < n) { off[i0 + 2] = e + v0 + v1; cursor[i0 + 2] = e + v0 + v1; }
        if (i0 + 3 < n) { off[i0 + 3] = e + v0 + v1 + v2; cursor[i0 + 3] = e + v0 + v1 + v2; }
        __syncthreads();                       // all reads of wsum/carry done
        if (t == 0) carry_s += total;
        __syncthreads();                       // carry visible; wsum reusable
    }
    if (t == 0) off[n] = carry_s;
}

// reorder: permS[pos] = original edge id; metaS[pos] = {src, cutoff-bits}
__global__ __launch_bounds__(256) void reorder_kernel(
    const int* __restrict__ eidx, const float* __restrict__ elen,
    int* __restrict__ cursor, int* __restrict__ permS,
    int2* __restrict__ metaS, int E)
{
    int i = blockIdx.x * 256 + threadIdx.x;
    int stride = gridDim.x * 256;
    for (; i < E; i += stride) {
        int dst = eidx[E + i];
        int pos = atomicAdd(&cursor[dst], 1);
        permS[pos] = i;
        float len = elen[i];
        bool ok = (len <= 10.0f) && (len >= 0.0f);
        float cv = ok ? 0.5f * (__cosf(len * 0.31415927f) + 1.0f) : 0.0f;
        metaS[pos] = make_int2(eidx[i], __float_as_int(cv));
    }
}

// egather: eattrS[j] = bf16(eattr[permS[j]])  -- sorted, bf16, 128B/edge.
// 8 lanes per edge; writes are fully streaming.
__global__ __launch_bounds__(256) void egather_kernel(
    const float* __restrict__ eattr, const int* __restrict__ permS,
    short* __restrict__ eattrS, int E)
{
    long total = (long)E * 8;
    long stride = (long)gridDim.x * 256;
    for (long t = (long)blockIdx.x * 256 + threadIdx.x; t < total; t += stride) {
        int j = (int)(t >> 3), sub = (int)(t & 7);
        int pe = permS[j];
        const float* sp = eattr + (size_t)pe * 64 + sub * 8;
        float4 a = *(const float4*)sp;
        float4 b = *(const float4*)(sp + 4);
        bf16x8 o;
        o[0] = bf16s(a.x); o[1] = bf16s(a.y); o[2] = bf16s(a.z); o[3] = bf16s(a.w);
        o[4] = bf16s(b.x); o[5] = bf16s(b.y); o[6] = bf16s(b.z); o[7] = bf16s(b.w);
        *(bf16x8*)(eattrS + (size_t)j * 64 + sub * 8) = o;
    }
}

// ---------------------------------------------------------------------------
// Kernel 2 (pull): one wave per dst node; 16 sorted edges/batch through the
// MFMA edge-MLP. Layer-2 MFMA is TRANSPOSED: mfma(bw2, ta, .) gives
// D[M=W-col within nt][N=edge], so lane (m,q) reg r holds
// W[edge m][col 16nt+4q+r] -> h-gather is 8x dwordx4 of 4-consecutive cols,
// meta one int2. Node reduce: butterfly over the 16 m-lanes.
// ---------------------------------------------------------------------------
template<bool PG>
__global__ __launch_bounds__(512, 2) void pull_kernel(
    const short* __restrict__ eattrS, const float* __restrict__ eattr,
    const int* __restrict__ permS, const int2* __restrict__ metaS,
    const int* __restrict__ off,
    const float* __restrict__ w1, const float* __restrict__ b1,
    const float* __restrict__ w2, const float* __restrict__ b2,
    const float* __restrict__ h, float* __restrict__ agg, int n)
{
    __shared__ short w1T[128 * 72] __attribute__((aligned(16)));   // 18 KB
    __shared__ short w2T[128 * 136] __attribute__((aligned(16)));  // 34 KB
    __shared__ short tseg[8 * 16 * 40] __attribute__((aligned(16))); // 10 KB
    __shared__ float b1s[128] __attribute__((aligned(16)));
    __shared__ float b2s[128] __attribute__((aligned(16)));

    for (int i = threadIdx.x; i < 64 * 128; i += 512) {
        int k = i >> 7, nn = i & 127;
        w1T[nn * 72 + k] = bf16s(w1[i]);
    }
    for (int i = threadIdx.x; i < 128 * 128; i += 512) {
        int k = i >> 7, nn = i & 127;
        w2T[nn * 136 + k] = bf16s(w2[i]);
    }
    if (threadIdx.x < 128) {
        b1s[threadIdx.x] = b1[threadIdx.x];
        b2s[threadIdx.x] = b2[threadIdx.x];
    }
    __syncthreads();

    const int lane = threadIdx.x & 63;
    const int m = lane & 15;        // this lane's edge-in-batch / A,B row idx
    const int q = lane >> 4;        // k-quad / col-quad
    short* tw = tseg + (threadIdx.x >> 6) * (16 * 40);

    int wid = blockIdx.x * 8 + (threadIdx.x >> 6);
    int nwaves = gridDim.x * 8;

    for (int node = wid; node < n; node += nwaves) {
        int o0 = off[node], o1 = off[node + 1];

        f32x4 aggv[8];
#pragma unroll
        for (int nt = 0; nt < 8; ++nt) { f32x4 z = {0,0,0,0}; aggv[nt] = z; }

        for (int b0 = o0; b0 < o1; b0 += 16) {
            // ---- A fragments for sorted edge b0+m (clamped; padded edges
            //      contribute garbage columns killed by cv=0 in epilogue)
            int pa = b0 + m;
            if (pa >= o1) pa = o1 - 1;
            bf16x8 af0, af1;
            if constexpr (PG) {
                const short* ep = eattrS + (size_t)pa * 64;
                af0 = *(const bf16x8*)(ep + q * 8);
                af1 = *(const bf16x8*)(ep + 32 + q * 8);
            } else {
                int pe = permS[pa];
                const float* ap = eattr + (size_t)pe * 64 + q * 8;
                float4 x0 = *(const float4*)(ap);
                float4 x1 = *(const float4*)(ap + 4);
                float4 x2 = *(const float4*)(ap + 32);
                float4 x3 = *(const float4*)(ap + 36);
                af0[0] = bf16s(x0.x); af0[1] = bf16s(x0.y);
                af0[2] = bf16s(x0.z); af0[3] = bf16s(x0.w);
                af0[4] = bf16s(x1.x); af0[5] = bf16s(x1.y);
                af0[6] = bf16s(x1.z); af0[7] = bf16s(x1.w);
                af1[0] = bf16s(x2.x); af1[1] = bf16s(x2.y);
                af1[2] = bf16s(x2.z); af1[3] = bf16s(x2.w);
                af1[4] = bf16s(x3.x); af1[5] = bf16s(x3.y);
                af1[6] = bf16s(x3.z); af1[7] = bf16s(x3.w);
            }

            // ---- this lane's edge meta (edge m): one int2
            int p = b0 + m;
            bool valid = (p < o1);
            int2 ms = metaS[valid ? p : o0];
            float cv = valid ? __int_as_float(ms.y) : 0.0f;
            int src = ms.x;

            // ---- layer-2 accumulators, TRANSPOSED: acc2[nt] reg r =
            //      W[edge m][col 16nt+4q+r]; init bias b2[16nt+4q+r]
            f32x4 acc2[8];
#pragma unroll
            for (int nt = 0; nt < 8; ++nt)
                acc2[nt] = *(const f32x4*)&b2s[nt * 16 + 4 * q];

            // ---- fused layer1 -> ssp -> layer2, 32 t-columns at a time
#pragma unroll
            for (int k2 = 0; k2 < 4; ++k2) {
                f32x4 acc1[2];
#pragma unroll
                for (int t = 0; t < 2; ++t) {
                    float bv = b1s[(2 * k2 + t) * 16 + m];
                    f32x4 c; c[0] = bv; c[1] = bv; c[2] = bv; c[3] = bv;
                    acc1[t] = c;
                }
#pragma unroll
                for (int t = 0; t < 2; ++t) {
#pragma unroll
                    for (int a = 0; a < 2; ++a) {
                        bf16x8 bw = *(const bf16x8*)&w1T[(16 * (2 * k2 + t) + m) * 72 + a * 32 + q * 8];
                        acc1[t] = __builtin_amdgcn_mfma_f32_16x16x32_bf16(
                            (a == 0) ? af0 : af1, bw, acc1[t], 0, 0, 0);
                    }
                }
                // t[edge 4q+r][col 16t+m] -> tseg
#pragma unroll
                for (int t = 0; t < 2; ++t) {
#pragma unroll
                    for (int r = 0; r < 4; ++r) {
                        tw[(4 * q + r) * 40 + 16 * t + m] = bf16s(sspf(acc1[t][r]));
                    }
                }
                // B-fragment (t of edge m); compiler inserts lgkmcnt wait
                bf16x8 ta = *(const bf16x8*)&tw[m * 40 + q * 8];
#pragma unroll
                for (int nt = 0; nt < 8; ++nt) {
                    bf16x8 bw2 = *(const bf16x8*)&w2T[(16 * nt + m) * 136 + k2 * 32 + q * 8];
                    // TRANSPOSED: D[M=col][N=edge] = w2^T . t^T
                    acc2[nt] = __builtin_amdgcn_mfma_f32_16x16x32_bf16(bw2, ta, acc2[nt], 0, 0, 0);
                }
            }

            // ---- epilogue: aggv[nt] += h[src][16nt+4q..+3] * W*cv
            if (cv != 0.0f) {
                const float* hp = h + ((size_t)src << 7) + 4 * q;
#pragma unroll
                for (int nt = 0; nt < 8; ++nt) {
                    f32x4 h4 = *(const f32x4*)(hp + nt * 16);
                    aggv[nt] = aggv[nt] + h4 * (acc2[nt] * cv);
                }
            }
        }

        // ---- reduce over the 16 m-lanes (butterfly; q-group preserved)
#pragma unroll
        for (int nt = 0; nt < 8; ++nt) {
            f32x4 v = aggv[nt];
#pragma unroll
            for (int msk = 1; msk < 16; msk <<= 1) {
                f32x4 o;
#pragma unroll
                for (int c = 0; c < 4; ++c) o[c] = __shfl_xor(v[c], msk, 64);
                v = v + o;
            }
            aggv[nt] = v;
        }
        // lane (0,q) writes cols {16nt+4q..+3}: 8 float4 stores x 4 lanes
        if (m == 0) {
            float* gp = agg + ((size_t)node << 7) + 4 * q;
#pragma unroll
            for (int nt = 0; nt < 8; ++nt)
                *(f32x4*)(gp + nt * 16) = aggv[nt];
        }
    }
}

// ---------------------------------------------------------------------------
// Kernel 3: out = ssp(agg @ lin2_w + lin2_b) @ lin_w + lin_b  (fp32 vector)
// ---------------------------------------------------------------------------
__global__ __launch_bounds__(256) void out_kernel(
    const float* __restrict__ agg,
    const float* __restrict__ w2, const float* __restrict__ b2,
    const float* __restrict__ w3, const float* __restrict__ b3,
    float* __restrict__ out, int n)
{
    __shared__ float aT[128 * 20];
    __shared__ float mT[128 * 20];
    int row0 = blockIdx.x * 16;
    for (int i = threadIdx.x; i < 2048; i += 256) {
        int r = i >> 7, c = i & 127;
        int rr = row0 + r;
        aT[c * 20 + r] = (rr < n) ? agg[(size_t)rr * 128 + c] : 0.0f;
    }
    __syncthreads();
    int j = threadIdx.x & 127;
    int rb = (threadIdx.x >> 7) * 8;

    float acc[8];
    float bj = b2[j];
#pragma unroll
    for (int r = 0; r < 8; ++r) acc[r] = bj;
    for (int k = 0; k < 128; ++k) {
        float wk = w2[k * 128 + j];
        const float4* xp = (const float4*)&aT[k * 20 + rb];
        float4 u0 = xp[0], u1 = xp[1];
        acc[0] = fmaf(u0.x, wk, acc[0]);
        acc[1] = fmaf(u0.y, wk, acc[1]);
        acc[2] = fmaf(u0.z, wk, acc[2]);
        acc[3] = fmaf(u0.w, wk, acc[3]);
        acc[4] = fmaf(u1.x, wk, acc[4]);
        acc[5] = fmaf(u1.y, wk, acc[5]);
        acc[6] = fmaf(u1.z, wk, acc[6]);
        acc[7] = fmaf(u1.w, wk, acc[7]);
    }
    float4 s0, s1;
    s0.x = sspf(acc[0]); s0.y = sspf(acc[1]); s0.z = sspf(acc[2]); s0.w = sspf(acc[3]);
    s1.x = sspf(acc[4]); s1.y = sspf(acc[5]); s1.z = sspf(acc[6]); s1.w = sspf(acc[7]);
    ((float4*)&mT[j * 20 + rb])[0] = s0;
    ((float4*)&mT[j * 20 + rb])[1] = s1;
    __syncthreads();

    float bj3 = b3[j];
#pragma unroll
    for (int r = 0; r < 8; ++r) acc[r] = bj3;
    for (int k = 0; k < 128; ++k) {
        float wk = w3[k * 128 + j];
        const float4* xp = (const float4*)&mT[k * 20 + rb];
        float4 u0 = xp[0], u1 = xp[1];
        acc[0] = fmaf(u0.x, wk, acc[0]);
        acc[1] = fmaf(u0.y, wk, acc[1]);
        acc[2] = fmaf(u0.z, wk, acc[2]);
        acc[3] = fmaf(u0.w, wk, acc[3]);
        acc[4] = fmaf(u1.x, wk, acc[4]);
        acc[5] = fmaf(u1.y, wk, acc[5]);
        acc[6] = fmaf(u1.z, wk, acc[6]);
        acc[7] = fmaf(u1.w, wk, acc[7]);
    }
#pragma unroll
    for (int r = 0; r < 8; ++r) {
        int rr = row0 + rb + r;
        if (rr < n) out[(size_t)rr * 128 + j] = acc[r];
    }
}

// ---------------------------------------------------------------------------
extern "C" void kernel_launch(void* const* d_in, const int* in_sizes, int n_in,
                              void* d_out, int out_size, void* d_ws, size_t ws_size,
                              hipStream_t stream)
{
    const float* x     = (const float*)d_in[0];
    const int*   eidx  = (const int*)d_in[1];
    const float* elen  = (const float*)d_in[2];
    const float* eattr = (const float*)d_in[3];
    const float* lin1w = (const float*)d_in[4];
    const float* nnw1  = (const float*)d_in[5];
    const float* nnb1  = (const float*)d_in[6];
    const float* nnw2  = (const float*)d_in[7];
    const float* nnb2  = (const float*)d_in[8];
    const float* lin2w = (const float*)d_in[9];
    const float* lin2b = (const float*)d_in[10];
    const float* linw  = (const float*)d_in[11];
    const float* linb  = (const float*)d_in[12];

    int n = in_sizes[0] / 128;   // 50000
    int E = in_sizes[2];         // 1.6M

    // workspace layout
    float* h      = (float*)d_ws;                   // n*128 f32
    float* agg    = h + (size_t)n * 128;            // n*128 f32
    int*   counts = (int*)(agg + (size_t)n * 128);  // n
    int*   off    = counts + n;                     // n+2 (pad for 8B align)
    int*   cursor = off + n + 2;                    // n
    int*   permS  = cursor + n;                     // E
    int2*  metaS  = (int2*)(permS + E);             // E (8B each)
    short* eattrS = (short*)(metaS + E);            // E*64 bf16 (205 MB)

    size_t base_bytes = (char*)eattrS - (char*)d_ws;
    size_t full_bytes = base_bytes + (size_t)E * 64 * sizeof(short);
    bool pregather = (ws_size >= full_bytes);

    hipMemsetAsync(counts, 0, (size_t)n * sizeof(int), stream);

    node_proj_kernel<<<(n + 15) / 16, 256, 0, stream>>>(x, lin1w, h, n);
    hist_kernel<<<2048, 256, 0, stream>>>(eidx, counts, E);
    scan_kernel<<<1, 1024, 0, stream>>>(counts, off, cursor, n);
    reorder_kernel<<<2048, 256, 0, stream>>>(eidx, elen, cursor, permS, metaS, E);
    if (pregather) {
        egather_kernel<<<2048, 256, 0, stream>>>(eattr, permS, eattrS, E);
        pull_kernel<true><<<512, 512, 0, stream>>>(eattrS, eattr, permS, metaS, off,
                                                   nnw1, nnb1, nnw2, nnb2, h, agg, n);
    } else {
        pull_kernel<false><<<512, 512, 0, stream>>>(eattrS, eattr, permS, metaS, off,
                                                    nnw1, nnb1, nnw2, nnb2, h, agg, n);
    }
    out_kernel<<<(n + 15) / 16, 256, 0, stream>>>(agg, lin2w, lin2b, linw, linb,
                                                  (float*)d_out, n);
}

// Round 6
// 1450.173 us; speedup vs baseline: 1.3169x; 1.3169x over previous
//
#include <hip/hip_runtime.h>

// ---------------------------------------------------------------------------
// InteractionBlock: W = ssp(attr@w1+b1)@w2+b2; W *= cutoff(len);
// h = x@lin1_w; agg[dst] += h[src]*W; out = ssp(agg@lin2_w+b)@lin_w+b
// N=50000, E=1.6M, HID=NF=128, NG=64
// R8 (= R7 resubmit after infra failure): SPLIT the fused pull kernel.
//     R4-R6 all spilled ~1-2.5GB because msg=h*W needs acc2(32) + aggv(32)
//     + h-load results(32) live at once under the unified VGPR/AGPR budget.
//     Split at the seam:
//       wcomp: sorted-order W*cv -> bf16 Wbuf (MFMA, ~70 live regs, no spill)
//       agg:   per-node reduce, no MFMA, ~15 live regs, h is L3-resident.
//     Wbuf round-trip costs ~130us streaming vs ~2.5GB scratch removed.
// ---------------------------------------------------------------------------

typedef __attribute__((ext_vector_type(8))) short bf16x8;
typedef __attribute__((ext_vector_type(4))) short short4v;
typedef __attribute__((ext_vector_type(4))) float f32x4;

static __device__ __forceinline__ float sspf(float v) {
    return fmaxf(v, 0.0f) + __logf(1.0f + __expf(-fabsf(v))) - 0.69314718f;
}

// fp32 -> bf16 round-to-nearest-even
static __device__ __forceinline__ short bf16s(float x) {
    unsigned u = __builtin_bit_cast(unsigned, x);
    return (short)((u + 0x7fffu + ((u >> 16) & 1u)) >> 16);
}

// ---------------------------------------------------------------------------
// Kernel 1: h = x @ lin1_w   [N,128] = [N,128]@[128,128]  (fp32 vector)
// ---------------------------------------------------------------------------
__global__ __launch_bounds__(256) void node_proj_kernel(
    const float* __restrict__ x, const float* __restrict__ w,
    float* __restrict__ h, int n)
{
    __shared__ float xsT[128 * 20];   // [k][row], pitch 20 floats
    int row0 = blockIdx.x * 16;
    for (int i = threadIdx.x; i < 2048; i += 256) {
        int r = i >> 7, c = i & 127;
        int rr = row0 + r;
        xsT[c * 20 + r] = (rr < n) ? x[(size_t)rr * 128 + c] : 0.0f;
    }
    __syncthreads();
    int j = threadIdx.x & 127;
    int rb = (threadIdx.x >> 7) * 8;
    float acc[8] = {0, 0, 0, 0, 0, 0, 0, 0};
    for (int k = 0; k < 128; ++k) {
        float wk = w[k * 128 + j];
        const float4* xp = (const float4*)&xsT[k * 20 + rb];
        float4 u0 = xp[0], u1 = xp[1];
        acc[0] = fmaf(u0.x, wk, acc[0]);
        acc[1] = fmaf(u0.y, wk, acc[1]);
        acc[2] = fmaf(u0.z, wk, acc[2]);
        acc[3] = fmaf(u0.w, wk, acc[3]);
        acc[4] = fmaf(u1.x, wk, acc[4]);
        acc[5] = fmaf(u1.y, wk, acc[5]);
        acc[6] = fmaf(u1.z, wk, acc[6]);
        acc[7] = fmaf(u1.w, wk, acc[7]);
    }
#pragma unroll
    for (int r = 0; r < 8; ++r) {
        int rr = row0 + rb + r;
        if (rr < n) h[(size_t)rr * 128 + j] = acc[r];
    }
}

// ---------------------------------------------------------------------------
// Sort machinery: counting sort of edges by dst.
// ---------------------------------------------------------------------------
__global__ __launch_bounds__(256) void hist_kernel(
    const int* __restrict__ eidx, int* __restrict__ counts, int E)
{
    int i = blockIdx.x * 256 + threadIdx.x;
    int stride = gridDim.x * 256;
    for (; i < E; i += stride) atomicAdd(&counts[eidx[E + i]], 1);
}

// exclusive scan of counts[0..n-1] -> off[0..n] and cursor copy; 1 block.
__global__ __launch_bounds__(1024) void scan_kernel(
    const int* __restrict__ counts, int* __restrict__ off,
    int* __restrict__ cursor, int n)
{
    __shared__ int wsum[16];
    __shared__ int carry_s;
    int t = threadIdx.x;
    int lane = t & 63, w = t >> 6;
    if (t == 0) carry_s = 0;
    __syncthreads();
    for (int base = 0; base < n; base += 4096) {
        int i0 = base + t * 4;
        int v0 = (i0 < n) ? counts[i0] : 0;
        int v1 = (i0 + 1 < n) ? counts[i0 + 1] : 0;
        int v2 = (i0 + 2 < n) ? counts[i0 + 2] : 0;
        int v3 = (i0 + 3 < n) ? counts[i0 + 3] : 0;
        int lsum = v0 + v1 + v2 + v3;
        int s = lsum;
#pragma unroll
        for (int d = 1; d < 64; d <<= 1) {
            int u = __shfl_up(s, d, 64);
            if (lane >= d) s += u;
        }
        if (lane == 63) wsum[w] = s;
        __syncthreads();
        if (w == 0) {
            int ws = (lane < 16) ? wsum[lane] : 0;
#pragma unroll
            for (int d = 1; d < 16; d <<= 1) {
                int u = __shfl_up(ws, d, 64);
                if (lane >= d) ws += u;
            }
            if (lane < 16) wsum[lane] = ws;   // inclusive wave totals
        }
        __syncthreads();
        int waveoff = (w > 0) ? wsum[w - 1] : 0;
        int total = wsum[15];
        int e = carry_s + waveoff + s - lsum;
        if (i0 < n)     { off[i0] = e;               cursor[i0] = e; }
        if (i0 + 1 < n) { off[i0 + 1] = e + v0;      cursor[i0 + 1] = e + v0; }
        if (i0 + 2 < n) { off[i0 + 2] = e + v0 + v1; cursor[i0 + 2] = e + v0 + v1; }
        if (i0 + 3 < n) { off[i0 + 3] = e + v0 + v1 + v2; cursor[i0 + 3] = e + v0 + v1 + v2; }
        __syncthreads();                       // all reads of wsum/carry done
        if (t == 0) carry_s += total;
        __syncthreads();                       // carry visible; wsum reusable
    }
    if (t == 0) off[n] = carry_s;
}

// reorder: permS[pos] = original edge id; metaS[pos] = {src, cutoff-bits}
__global__ __launch_bounds__(256) void reorder_kernel(
    const int* __restrict__ eidx, const float* __restrict__ elen,
    int* __restrict__ cursor, int* __restrict__ permS,
    int2* __restrict__ metaS, int E)
{
    int i = blockIdx.x * 256 + threadIdx.x;
    int stride = gridDim.x * 256;
    for (; i < E; i += stride) {
        int dst = eidx[E + i];
        int pos = atomicAdd(&cursor[dst], 1);
        permS[pos] = i;
        float len = elen[i];
        bool ok = (len <= 10.0f) && (len >= 0.0f);
        float cv = ok ? 0.5f * (__cosf(len * 0.31415927f) + 1.0f) : 0.0f;
        metaS[pos] = make_int2(eidx[i], __float_as_int(cv));
    }
}

// ---------------------------------------------------------------------------
// Phase A (wcomp): W*cv for all edges in SORTED order -> bf16 Wbuf[E][128].
// 16 edges/wave/batch through the MFMA edge-MLP. Layer-2 MFMA transposed
// (verified R6): lane (m,q) reg r holds W[edge m][col 16nt+4q+r].
// No aggv, no h-gather -> live set ~70 regs, no spill.
// ---------------------------------------------------------------------------
__global__ __launch_bounds__(512, 2) void wcomp_kernel(
    const float* __restrict__ eattr, const int* __restrict__ permS,
    const int2* __restrict__ metaS,
    const float* __restrict__ w1, const float* __restrict__ b1,
    const float* __restrict__ w2, const float* __restrict__ b2,
    short* __restrict__ Wbuf, int E)
{
    __shared__ short w1T[128 * 72] __attribute__((aligned(16)));   // 18 KB
    __shared__ short w2T[128 * 136] __attribute__((aligned(16)));  // 34 KB
    __shared__ short tseg[8 * 16 * 40] __attribute__((aligned(16))); // 10 KB
    __shared__ float b1s[128] __attribute__((aligned(16)));
    __shared__ float b2s[128] __attribute__((aligned(16)));

    for (int i = threadIdx.x; i < 64 * 128; i += 512) {
        int k = i >> 7, nn = i & 127;
        w1T[nn * 72 + k] = bf16s(w1[i]);
    }
    for (int i = threadIdx.x; i < 128 * 128; i += 512) {
        int k = i >> 7, nn = i & 127;
        w2T[nn * 136 + k] = bf16s(w2[i]);
    }
    if (threadIdx.x < 128) {
        b1s[threadIdx.x] = b1[threadIdx.x];
        b2s[threadIdx.x] = b2[threadIdx.x];
    }
    __syncthreads();

    const int lane = threadIdx.x & 63;
    const int m = lane & 15;        // this lane's edge-in-batch
    const int q = lane >> 4;        // k-quad / col-quad
    short* tw = tseg + (threadIdx.x >> 6) * (16 * 40);

    int nb = (E + 15) >> 4;
    int wid = blockIdx.x * 8 + (threadIdx.x >> 6);
    int nwaves = gridDim.x * 8;

    for (int g = wid; g < nb; g += nwaves) {
        int e = (g << 4) + m;           // this lane's sorted edge
        int ec = (e < E) ? e : E - 1;

        // ---- A fragments: gather eattr[permS[e]], cvt to bf16
        int pe = permS[ec];
        const float* ap = eattr + (size_t)pe * 64 + q * 8;
        float4 x0 = *(const float4*)(ap);
        float4 x1 = *(const float4*)(ap + 4);
        float4 x2 = *(const float4*)(ap + 32);
        float4 x3 = *(const float4*)(ap + 36);
        bf16x8 af0, af1;
        af0[0] = bf16s(x0.x); af0[1] = bf16s(x0.y);
        af0[2] = bf16s(x0.z); af0[3] = bf16s(x0.w);
        af0[4] = bf16s(x1.x); af0[5] = bf16s(x1.y);
        af0[6] = bf16s(x1.z); af0[7] = bf16s(x1.w);
        af1[0] = bf16s(x2.x); af1[1] = bf16s(x2.y);
        af1[2] = bf16s(x2.z); af1[3] = bf16s(x2.w);
        af1[4] = bf16s(x3.x); af1[5] = bf16s(x3.y);
        af1[6] = bf16s(x3.z); af1[7] = bf16s(x3.w);

        float cv = (e < E) ? __int_as_float(metaS[e].y) : 0.0f;

        // ---- layer-2 accumulators (transposed layout), init b2[16nt+4q+r]
        f32x4 acc2[8];
#pragma unroll
        for (int nt = 0; nt < 8; ++nt)
            acc2[nt] = *(const f32x4*)&b2s[nt * 16 + 4 * q];

        // ---- fused layer1 -> ssp -> layer2, 32 t-columns at a time
#pragma unroll
        for (int k2 = 0; k2 < 4; ++k2) {
            f32x4 acc1[2];
#pragma unroll
            for (int t = 0; t < 2; ++t) {
                float bv = b1s[(2 * k2 + t) * 16 + m];
                f32x4 c; c[0] = bv; c[1] = bv; c[2] = bv; c[3] = bv;
                acc1[t] = c;
            }
#pragma unroll
            for (int t = 0; t < 2; ++t) {
#pragma unroll
                for (int a = 0; a < 2; ++a) {
                    bf16x8 bw = *(const bf16x8*)&w1T[(16 * (2 * k2 + t) + m) * 72 + a * 32 + q * 8];
                    acc1[t] = __builtin_amdgcn_mfma_f32_16x16x32_bf16(
                        (a == 0) ? af0 : af1, bw, acc1[t], 0, 0, 0);
                }
            }
            // t[edge 4q+r][col 16t+m] -> tseg
#pragma unroll
            for (int t = 0; t < 2; ++t) {
#pragma unroll
                for (int r = 0; r < 4; ++r) {
                    tw[(4 * q + r) * 40 + 16 * t + m] = bf16s(sspf(acc1[t][r]));
                }
            }
            // B-fragment (t of edge m); compiler inserts lgkmcnt wait
            bf16x8 ta = *(const bf16x8*)&tw[m * 40 + q * 8];
#pragma unroll
            for (int nt = 0; nt < 8; ++nt) {
                bf16x8 bw2 = *(const bf16x8*)&w2T[(16 * nt + m) * 136 + k2 * 32 + q * 8];
                // TRANSPOSED: D[M=col][N=edge] = w2^T . t^T
                acc2[nt] = __builtin_amdgcn_mfma_f32_16x16x32_bf16(bw2, ta, acc2[nt], 0, 0, 0);
            }
        }

        // ---- store W*cv as bf16: lane (m,q) -> Wbuf[e][16nt+4q .. +3]
        if (e < E) {
            short* wp = Wbuf + ((size_t)e << 7) + 4 * q;
#pragma unroll
            for (int nt = 0; nt < 8; ++nt) {
                f32x4 v = acc2[nt] * cv;
                short4v s;
                s[0] = bf16s(v[0]); s[1] = bf16s(v[1]);
                s[2] = bf16s(v[2]); s[3] = bf16s(v[3]);
                *(short4v*)(wp + nt * 16) = s;
            }
        }
    }
}

// ---------------------------------------------------------------------------
// Phase B (agg): agg[node] = sum_e h[src(e)] * Wbuf[e].  One wave per node;
// lane l owns cols {2l, 2l+1}. Coalesced Wbuf row reads (256B/edge),
// broadcast meta, h is L3-resident. No MFMA, ~15 live regs.
// ---------------------------------------------------------------------------
__global__ __launch_bounds__(256) void agg_kernel(
    const short* __restrict__ Wbuf, const int2* __restrict__ metaS,
    const int* __restrict__ off, const float* __restrict__ h,
    float* __restrict__ agg, int n)
{
    int lane = threadIdx.x & 63;
    int node = blockIdx.x * 4 + (threadIdx.x >> 6);
    if (node >= n) return;

    int o0 = off[node], o1 = off[node + 1];
    float a0 = 0.0f, a1 = 0.0f;
    for (int p = o0; p < o1; ++p) {
        int src = metaS[p].x;                 // broadcast (same addr all lanes)
        unsigned u = *(const unsigned*)(Wbuf + ((size_t)p << 7) + 2 * lane);
        float2 h2 = *(const float2*)(h + ((size_t)src << 7) + 2 * lane);
        float w0 = __uint_as_float(u << 16);          // col 2l
        float w1 = __uint_as_float(u & 0xffff0000u);  // col 2l+1
        a0 = fmaf(h2.x, w0, a0);
        a1 = fmaf(h2.y, w1, a1);
    }
    float2 o; o.x = a0; o.y = a1;
    *(float2*)(agg + ((size_t)node << 7) + 2 * lane) = o;
}

// ---------------------------------------------------------------------------
// Fallback (ws too small): R6 fused pull kernel, f32 gather path.
// ---------------------------------------------------------------------------
__global__ __launch_bounds__(512, 2) void pull_fallback_kernel(
    const float* __restrict__ eattr,
    const int* __restrict__ permS, const int2* __restrict__ metaS,
    const int* __restrict__ off,
    const float* __restrict__ w1, const float* __restrict__ b1,
    const float* __restrict__ w2, const float* __restrict__ b2,
    const float* __restrict__ h, float* __restrict__ agg, int n)
{
    __shared__ short w1T[128 * 72] __attribute__((aligned(16)));
    __shared__ short w2T[128 * 136] __attribute__((aligned(16)));
    __shared__ short tseg[8 * 16 * 40] __attribute__((aligned(16)));
    __shared__ float b1s[128] __attribute__((aligned(16)));
    __shared__ float b2s[128] __attribute__((aligned(16)));

    for (int i = threadIdx.x; i < 64 * 128; i += 512) {
        int k = i >> 7, nn = i & 127;
        w1T[nn * 72 + k] = bf16s(w1[i]);
    }
    for (int i = threadIdx.x; i < 128 * 128; i += 512) {
        int k = i >> 7, nn = i & 127;
        w2T[nn * 136 + k] = bf16s(w2[i]);
    }
    if (threadIdx.x < 128) {
        b1s[threadIdx.x] = b1[threadIdx.x];
        b2s[threadIdx.x] = b2[threadIdx.x];
    }
    __syncthreads();

    const int lane = threadIdx.x & 63;
    const int m = lane & 15;
    const int q = lane >> 4;
    short* tw = tseg + (threadIdx.x >> 6) * (16 * 40);

    int wid = blockIdx.x * 8 + (threadIdx.x >> 6);
    int nwaves = gridDim.x * 8;

    for (int node = wid; node < n; node += nwaves) {
        int o0 = off[node], o1 = off[node + 1];
        f32x4 aggv[8];
#pragma unroll
        for (int nt = 0; nt < 8; ++nt) { f32x4 z = {0,0,0,0}; aggv[nt] = z; }

        for (int b0 = o0; b0 < o1; b0 += 16) {
            int pa = b0 + m;
            if (pa >= o1) pa = o1 - 1;
            int pe = permS[pa];
            const float* ap = eattr + (size_t)pe * 64 + q * 8;
            float4 x0 = *(const float4*)(ap);
            float4 x1 = *(const float4*)(ap + 4);
            float4 x2 = *(const float4*)(ap + 32);
            float4 x3 = *(const float4*)(ap + 36);
            bf16x8 af0, af1;
            af0[0] = bf16s(x0.x); af0[1] = bf16s(x0.y);
            af0[2] = bf16s(x0.z); af0[3] = bf16s(x0.w);
            af0[4] = bf16s(x1.x); af0[5] = bf16s(x1.y);
            af0[6] = bf16s(x1.z); af0[7] = bf16s(x1.w);
            af1[0] = bf16s(x2.x); af1[1] = bf16s(x2.y);
            af1[2] = bf16s(x2.z); af1[3] = bf16s(x2.w);
            af1[4] = bf16s(x3.x); af1[5] = bf16s(x3.y);
            af1[6] = bf16s(x3.z); af1[7] = bf16s(x3.w);

            int p = b0 + m;
            bool valid = (p < o1);
            int2 ms = metaS[valid ? p : o0];
            float cv = valid ? __int_as_float(ms.y) : 0.0f;
            int src = ms.x;

            f32x4 acc2[8];
#pragma unroll
            for (int nt = 0; nt < 8; ++nt)
                acc2[nt] = *(const f32x4*)&b2s[nt * 16 + 4 * q];

#pragma unroll
            for (int k2 = 0; k2 < 4; ++k2) {
                f32x4 acc1[2];
#pragma unroll
                for (int t = 0; t < 2; ++t) {
                    float bv = b1s[(2 * k2 + t) * 16 + m];
                    f32x4 c; c[0] = bv; c[1] = bv; c[2] = bv; c[3] = bv;
                    acc1[t] = c;
                }
#pragma unroll
                for (int t = 0; t < 2; ++t) {
#pragma unroll
                    for (int a = 0; a < 2; ++a) {
                        bf16x8 bw = *(const bf16x8*)&w1T[(16 * (2 * k2 + t) + m) * 72 + a * 32 + q * 8];
                        acc1[t] = __builtin_amdgcn_mfma_f32_16x16x32_bf16(
                            (a == 0) ? af0 : af1, bw, acc1[t], 0, 0, 0);
                    }
                }
#pragma unroll
                for (int t = 0; t < 2; ++t) {
#pragma unroll
                    for (int r = 0; r < 4; ++r) {
                        tw[(4 * q + r) * 40 + 16 * t + m] = bf16s(sspf(acc1[t][r]));
                    }
                }
                bf16x8 ta = *(const bf16x8*)&tw[m * 40 + q * 8];
#pragma unroll
                for (int nt = 0; nt < 8; ++nt) {
                    bf16x8 bw2 = *(const bf16x8*)&w2T[(16 * nt + m) * 136 + k2 * 32 + q * 8];
                    acc2[nt] = __builtin_amdgcn_mfma_f32_16x16x32_bf16(bw2, ta, acc2[nt], 0, 0, 0);
                }
            }

            if (cv != 0.0f) {
                const float* hp = h + ((size_t)src << 7) + 4 * q;
#pragma unroll
                for (int nt = 0; nt < 8; ++nt) {
                    f32x4 h4 = *(const f32x4*)(hp + nt * 16);
                    aggv[nt] = aggv[nt] + h4 * (acc2[nt] * cv);
                }
            }
        }

#pragma unroll
        for (int nt = 0; nt < 8; ++nt) {
            f32x4 v = aggv[nt];
#pragma unroll
            for (int msk = 1; msk < 16; msk <<= 1) {
                f32x4 o;
#pragma unroll
                for (int c = 0; c < 4; ++c) o[c] = __shfl_xor(v[c], msk, 64);
                v = v + o;
            }
            aggv[nt] = v;
        }
        if (m == 0) {
            float* gp = agg + ((size_t)node << 7) + 4 * q;
#pragma unroll
            for (int nt = 0; nt < 8; ++nt)
                *(f32x4*)(gp + nt * 16) = aggv[nt];
        }
    }
}

// ---------------------------------------------------------------------------
// Kernel 3: out = ssp(agg @ lin2_w + lin2_b) @ lin_w + lin_b  (fp32 vector)
// ---------------------------------------------------------------------------
__global__ __launch_bounds__(256) void out_kernel(
    const float* __restrict__ agg,
    const float* __restrict__ w2, const float* __restrict__ b2,
    const float* __restrict__ w3, const float* __restrict__ b3,
    float* __restrict__ out, int n)
{
    __shared__ float aT[128 * 20];
    __shared__ float mT[128 * 20];
    int row0 = blockIdx.x * 16;
    for (int i = threadIdx.x; i < 2048; i += 256) {
        int r = i >> 7, c = i & 127;
        int rr = row0 + r;
        aT[c * 20 + r] = (rr < n) ? agg[(size_t)rr * 128 + c] : 0.0f;
    }
    __syncthreads();
    int j = threadIdx.x & 127;
    int rb = (threadIdx.x >> 7) * 8;

    float acc[8];
    float bj = b2[j];
#pragma unroll
    for (int r = 0; r < 8; ++r) acc[r] = bj;
    for (int k = 0; k < 128; ++k) {
        float wk = w2[k * 128 + j];
        const float4* xp = (const float4*)&aT[k * 20 + rb];
        float4 u0 = xp[0], u1 = xp[1];
        acc[0] = fmaf(u0.x, wk, acc[0]);
        acc[1] = fmaf(u0.y, wk, acc[1]);
        acc[2] = fmaf(u0.z, wk, acc[2]);
        acc[3] = fmaf(u0.w, wk, acc[3]);
        acc[4] = fmaf(u1.x, wk, acc[4]);
        acc[5] = fmaf(u1.y, wk, acc[5]);
        acc[6] = fmaf(u1.z, wk, acc[6]);
        acc[7] = fmaf(u1.w, wk, acc[7]);
    }
    float4 s0, s1;
    s0.x = sspf(acc[0]); s0.y = sspf(acc[1]); s0.z = sspf(acc[2]); s0.w = sspf(acc[3]);
    s1.x = sspf(acc[4]); s1.y = sspf(acc[5]); s1.z = sspf(acc[6]); s1.w = sspf(acc[7]);
    ((float4*)&mT[j * 20 + rb])[0] = s0;
    ((float4*)&mT[j * 20 + rb])[1] = s1;
    __syncthreads();

    float bj3 = b3[j];
#pragma unroll
    for (int r = 0; r < 8; ++r) acc[r] = bj3;
    for (int k = 0; k < 128; ++k) {
        float wk = w3[k * 128 + j];
        const float4* xp = (const float4*)&mT[k * 20 + rb];
        float4 u0 = xp[0], u1 = xp[1];
        acc[0] = fmaf(u0.x, wk, acc[0]);
        acc[1] = fmaf(u0.y, wk, acc[1]);
        acc[2] = fmaf(u0.z, wk, acc[2]);
        acc[3] = fmaf(u0.w, wk, acc[3]);
        acc[4] = fmaf(u1.x, wk, acc[4]);
        acc[5] = fmaf(u1.y, wk, acc[5]);
        acc[6] = fmaf(u1.z, wk, acc[6]);
        acc[7] = fmaf(u1.w, wk, acc[7]);
    }
#pragma unroll
    for (int r = 0; r < 8; ++r) {
        int rr = row0 + rb + r;
        if (rr < n) out[(size_t)rr * 128 + j] = acc[r];
    }
}

// ---------------------------------------------------------------------------
extern "C" void kernel_launch(void* const* d_in, const int* in_sizes, int n_in,
                              void* d_out, int out_size, void* d_ws, size_t ws_size,
                              hipStream_t stream)
{
    const float* x     = (const float*)d_in[0];
    const int*   eidx  = (const int*)d_in[1];
    const float* elen  = (const float*)d_in[2];
    const float* eattr = (const float*)d_in[3];
    const float* lin1w = (const float*)d_in[4];
    const float* nnw1  = (const float*)d_in[5];
    const float* nnb1  = (const float*)d_in[6];
    const float* nnw2  = (const float*)d_in[7];
    const float* nnb2  = (const float*)d_in[8];
    const float* lin2w = (const float*)d_in[9];
    const float* lin2b = (const float*)d_in[10];
    const float* linw  = (const float*)d_in[11];
    const float* linb  = (const float*)d_in[12];

    int n = in_sizes[0] / 128;   // 50000
    int E = in_sizes[2];         // 1.6M

    // workspace layout (16B-aligned sections)
    char* p = (char*)d_ws;
    auto alloc = [&](size_t bytes) {
        char* r = p;
        p += (bytes + 15) & ~(size_t)15;
        return (void*)r;
    };
    float* h      = (float*)alloc((size_t)n * 128 * 4);
    float* agg    = (float*)alloc((size_t)n * 128 * 4);
    int*   counts = (int*)alloc((size_t)n * 4);
    int*   off    = (int*)alloc((size_t)(n + 1) * 4);
    int*   cursor = (int*)alloc((size_t)n * 4);
    int*   permS  = (int*)alloc((size_t)E * 4);
    int2*  metaS  = (int2*)alloc((size_t)E * 8);
    short* Wbuf   = (short*)alloc((size_t)E * 128 * 2);   // 410 MB
    size_t need_full = (size_t)(p - (char*)d_ws);
    bool split = (ws_size >= need_full);

    hipMemsetAsync(counts, 0, (size_t)n * sizeof(int), stream);

    node_proj_kernel<<<(n + 15) / 16, 256, 0, stream>>>(x, lin1w, h, n);
    hist_kernel<<<2048, 256, 0, stream>>>(eidx, counts, E);
    scan_kernel<<<1, 1024, 0, stream>>>(counts, off, cursor, n);
    reorder_kernel<<<2048, 256, 0, stream>>>(eidx, elen, cursor, permS, metaS, E);
    if (split) {
        wcomp_kernel<<<512, 512, 0, stream>>>(eattr, permS, metaS,
                                              nnw1, nnb1, nnw2, nnb2, Wbuf, E);
        agg_kernel<<<(n + 3) / 4, 256, 0, stream>>>(Wbuf, metaS, off, h, agg, n);
    } else {
        pull_fallback_kernel<<<512, 512, 0, stream>>>(eattr, permS, metaS, off,
                                                      nnw1, nnb1, nnw2, nnb2,
                                                      h, agg, n);
    }
    out_kernel<<<(n + 15) / 16, 256, 0, stream>>>(agg, lin2w, lin2b, linw, linb,
                                                  (float*)d_out, n);
}